// Round 3
// baseline (553.820 us; speedup 1.0000x reference)
//
#include <hip/hip_runtime.h>
#include <hip/hip_bf16.h>
#include <stdint.h>

#define B_ 128
#define C_ 512
#define H_ 8
#define W_ 64
#define L_ 512
#define EMB_ 512
#define HID_ 512
#define M_ 65536
#define PH 10
#define PW 66
#define PADSZ (B_*PH*PW*C_)     /* bf16 elements: 43,253,760 */
#define BT_SZ (9*EMB_*C_)       /* bf16 elements: 2,359,296  */
#define GEM_SZ (B_*EMB_)        /* f32 */

typedef __attribute__((ext_vector_type(8))) short short8;
typedef __attribute__((ext_vector_type(4))) float f32x4;

__device__ __forceinline__ void gload16(const void* g, void* l) {
    __builtin_amdgcn_global_load_lds(
        (const __attribute__((address_space(1))) unsigned int*)g,
        (__attribute__((address_space(3))) unsigned int*)l, 16, 0, 0);
}

// ---- pad + transpose conv_f [B,C,H,W] f32 -> padded channel-last bf16 [B][PH][PW][C]
__global__ __launch_bounds__(256) void k_pad(const float* __restrict__ cf,
                                             __hip_bfloat16* __restrict__ pad) {
    int bid = blockIdx.x, t = threadIdx.x;
    int b = bid >> 3, y = bid & 7;
    for (int cc = 0; cc < 2; ++cc) {
        int c = cc * 256 + t;
        const float* src = cf + ((size_t)(b * C_ + c) * H_ + y) * W_;
        __hip_bfloat16* dst = pad + ((size_t)(b * PH + y + 1) * PW + 1) * C_ + c;
#pragma unroll
        for (int x = 0; x < W_; ++x)
            dst[(size_t)x * C_] = __float2bfloat16(src[x]);
    }
}

// ---- K_conv [EMB,C,3,3] f32 -> Bt [tap][e][c] bf16
__global__ __launch_bounds__(256) void k_wt(const float* __restrict__ kc,
                                            __hip_bfloat16* __restrict__ bt) {
    int e = blockIdx.x, t = threadIdx.x;
    for (int cc = 0; cc < 2; ++cc) {
        int c = cc * 256 + t;
        const float* src = kc + (size_t)(e * C_ + c) * 9;
#pragma unroll
        for (int tap = 0; tap < 9; ++tap)
            bt[(size_t)tap * EMB_ * C_ + e * C_ + c] = __float2bfloat16(src[tap]);
    }
}

// ---- g_em = h @ W_h^T + b_h  (fp32)
__global__ __launch_bounds__(256) void k_gem(const float* __restrict__ h,
                                             const float* __restrict__ Wh,
                                             const float* __restrict__ bh,
                                             float* __restrict__ gem) {
    int b = blockIdx.x, t = threadIdx.x;
    __shared__ float hs[HID_];
    hs[t] = h[b * HID_ + t];
    hs[t + 256] = h[b * HID_ + t + 256];
    __syncthreads();
    for (int e = t; e < EMB_; e += 256) {
        float acc = bh[e];
        const float4* wr = (const float4*)(Wh + (size_t)e * HID_);
#pragma unroll 4
        for (int k4 = 0; k4 < HID_ / 4; ++k4) {
            float4 w = wr[k4];
            const float* hp = &hs[k4 * 4];
            acc += w.x * hp[0] + w.y * hp[1] + w.z * hp[2] + w.w * hp[3];
        }
        gem[b * EMB_ + e] = acc;
    }
}

// ---- main conv-GEMM (implicit im2col) + fused tanh/watt epilogue -> score parts
// D[m,e] = sum_{tap,c} padded[b, y+dy, x+dx, c] * Bt[tap, e, c]
// tile 128x128, BK=64, 4 waves (2x2), 16x16x32 bf16 MFMA
__global__ __launch_bounds__(256) void k_conv(const __hip_bfloat16* __restrict__ pad,
                                              const __hip_bfloat16* __restrict__ bt,
                                              const float* __restrict__ gem,
                                              const float* __restrict__ bconv,
                                              const float* __restrict__ watt,
                                              float* __restrict__ sp) {
    __shared__ __align__(16) char lds[32768];
    char* ldsA = lds;
    char* ldsB = lds + 16384;
    const int tid = threadIdx.x;
    const int lane = tid & 63, wid = tid >> 6;
    const int wm = wid >> 1, wn = wid & 1;
    int bid0 = blockIdx.x;
    int bid = (bid0 & 7) * 256 + (bid0 >> 3);   // XCD-aware swizzle (2048 % 8 == 0)
    const int tile_m = bid >> 2, tile_n = bid & 3;
    const int b = tile_m >> 2;

    // staging precompute: LDS slot s (linear, what global_load_lds writes) holds
    // logical (row, cbyte = (s&127) ^ ((row&7)<<4))  [both-sides swizzle, rule #21]
    int gA[4], gB[4];
#pragma unroll
    for (int i = 0; i < 4; ++i) {
        int s = i * 4096 + tid * 16;
        int row = s >> 7;
        int clocal = ((s & 127) ^ ((row & 7) << 4)) >> 1;
        int m = tile_m * 128 + row;
        int y = (m >> 6) & 7;
        int x = m & 63;
        gA[i] = ((b * PH + y) * PW + x) * C_ + clocal;   // tap (0,0) base
        int e = tile_n * 128 + row;
        gB[i] = e * C_ + clocal;
    }

    // ds_read bases (swizzled). row&7 == lane&7 for all fragments.
    const int la = lane & 15, lg = lane >> 4;
    const int xorv = (lane & 7) << 4;
    const int cb0 = (lg * 16) ^ xorv;
    const int cb1 = (64 + lg * 16) ^ xorv;
    const char* Ard0 = ldsA + (wm * 64 + la) * 128 + cb0;
    const char* Ard1 = ldsA + (wm * 64 + la) * 128 + cb1;
    const char* Brd0 = ldsB + (wn * 64 + la) * 128 + cb0;
    const char* Brd1 = ldsB + (wn * 64 + la) * 128 + cb1;

    f32x4 acc[4][4];
#pragma unroll
    for (int i = 0; i < 4; ++i)
#pragma unroll
        for (int j = 0; j < 4; ++j)
            acc[i][j] = (f32x4){0.f, 0.f, 0.f, 0.f};

    for (int tap = 0; tap < 9; ++tap) {
        const int dy = tap / 3, dx = tap - dy * 3;
        const int aoff = (dy * PW + dx) * C_;
        const size_t boff = (size_t)tap * EMB_ * C_;
        for (int c0 = 0; c0 < C_; c0 += 64) {
#pragma unroll
            for (int i = 0; i < 4; ++i) {
                gload16(pad + gA[i] + aoff + c0, ldsA + i * 4096 + wid * 1024);
                gload16(bt + boff + gB[i] + c0, ldsB + i * 4096 + wid * 1024);
            }
            __syncthreads();
#pragma unroll
            for (int kk = 0; kk < 2; ++kk) {
                short8 af[4], bfr[4];
#pragma unroll
                for (int fm = 0; fm < 4; ++fm)
                    af[fm] = *(const short8*)((kk ? Ard1 : Ard0) + fm * 2048);
#pragma unroll
                for (int fn = 0; fn < 4; ++fn)
                    bfr[fn] = *(const short8*)((kk ? Brd1 : Brd0) + fn * 2048);
#pragma unroll
                for (int fm = 0; fm < 4; ++fm)
#pragma unroll
                    for (int fn = 0; fn < 4; ++fn)
                        acc[fm][fn] = __builtin_amdgcn_mfma_f32_16x16x32_bf16(
                            af[fm], bfr[fn], acc[fm][fn], 0, 0, 0);
            }
            __syncthreads();
        }
    }

    // epilogue: score_part[part][m] = sum_e tanh(conv + b_conv + g_em) * w_att
    const int part = tile_n * 2 + wn;
    float addv[4], wv[4];
#pragma unroll
    for (int fn = 0; fn < 4; ++fn) {
        int e = tile_n * 128 + wn * 64 + fn * 16 + la;
        addv[fn] = bconv[e] + gem[b * EMB_ + e];
        wv[fn] = watt[e];
    }
#pragma unroll
    for (int fm = 0; fm < 4; ++fm) {
        float sj[4] = {0.f, 0.f, 0.f, 0.f};
#pragma unroll
        for (int fn = 0; fn < 4; ++fn)
#pragma unroll
            for (int j = 0; j < 4; ++j)
                sj[j] += tanhf(acc[fm][fn][j] + addv[fn]) * wv[fn];
#pragma unroll
        for (int mask = 1; mask < 16; mask <<= 1)
#pragma unroll
            for (int j = 0; j < 4; ++j)
                sj[j] += __shfl_xor(sj[j], mask, 64);
        if (la == 0) {
            int mrow = tile_m * 128 + wm * 64 + fm * 16 + lg * 4;
            *(float4*)(sp + (size_t)part * M_ + mrow) =
                make_float4(sj[0], sj[1], sj[2], sj[3]);
        }
    }
}

// ---- softmax over L per batch: score = b_att + sum parts -> alpha (written to d_out)
__global__ __launch_bounds__(512) void k_softmax(const float* __restrict__ sp,
                                                 const float* __restrict__ batt,
                                                 float* __restrict__ alpha) {
    int b = blockIdx.x, t = threadIdx.x;
    float s = batt[0];
#pragma unroll
    for (int p = 0; p < 8; ++p) s += sp[(size_t)p * M_ + b * L_ + t];
    int lane = t & 63, wid = t >> 6;
    __shared__ float red[8];
    float m = s;
#pragma unroll
    for (int mask = 1; mask < 64; mask <<= 1) m = fmaxf(m, __shfl_xor(m, mask, 64));
    if (lane == 0) red[wid] = m;
    __syncthreads();
    float M = red[0];
#pragma unroll
    for (int i = 1; i < 8; ++i) M = fmaxf(M, red[i]);
    float ev = __expf(s - M);
    float sum = ev;
#pragma unroll
    for (int mask = 1; mask < 64; mask <<= 1) sum += __shfl_xor(sum, mask, 64);
    __syncthreads();
    if (lane == 0) red[wid] = sum;
    __syncthreads();
    float S = 0.f;
#pragma unroll
    for (int i = 0; i < 8; ++i) S += red[i];
    alpha[b * L_ + t] = ev / S;
}

// ---- att_out[b,c] = sum_l alpha[b,l] * conv_f[b,c,l]  (f32, coalesced)
__global__ __launch_bounds__(256) void k_att(const float* __restrict__ cf,
                                             const float* __restrict__ alpha,
                                             float* __restrict__ att) {
    int bid = blockIdx.x;
    int b = bid >> 7, cg = bid & 127;
    int t = threadIdx.x, lane = t & 63, wid = t >> 6;
    int c = cg * 4 + wid;
    const float4* xr = (const float4*)(cf + (size_t)(b * C_ + c) * L_);
    const float4* ar = (const float4*)(alpha + b * L_);
    float acc = 0.f;
#pragma unroll
    for (int it = 0; it < 2; ++it) {
        float4 xv = xr[it * 64 + lane];
        float4 av = ar[it * 64 + lane];
        acc += xv.x * av.x + xv.y * av.y + xv.z * av.z + xv.w * av.w;
    }
#pragma unroll
    for (int mask = 1; mask < 64; mask <<= 1) acc += __shfl_xor(acc, mask, 64);
    if (lane == 0) att[b * C_ + c] = acc;
}

extern "C" void kernel_launch(void* const* d_in, const int* in_sizes, int n_in,
                              void* d_out, int out_size, void* d_ws, size_t ws_size,
                              hipStream_t stream) {
    const float* conv_f = (const float*)d_in[0];
    const float* h      = (const float*)d_in[1];
    const float* W_h    = (const float*)d_in[2];
    const float* b_h    = (const float*)d_in[3];
    const float* K_conv = (const float*)d_in[4];
    const float* b_conv = (const float*)d_in[5];
    const float* w_att  = (const float*)d_in[6];
    const float* b_att  = (const float*)d_in[7];
    float* out = (float*)d_out;              // [B*C] att_out then [B*L] alpha

    char* ws = (char*)d_ws;
    __hip_bfloat16* pad = (__hip_bfloat16*)ws;
    __hip_bfloat16* bt  = (__hip_bfloat16*)(ws + (size_t)PADSZ * 2);
    float* gem = (float*)(ws + (size_t)PADSZ * 2 + (size_t)BT_SZ * 2);
    float* sp  = gem + GEM_SZ;               // 8 * M_ floats

    hipMemsetAsync(pad, 0, (size_t)PADSZ * 2, stream);
    k_pad<<<B_ * H_, 256, 0, stream>>>(conv_f, pad);
    k_wt<<<EMB_, 256, 0, stream>>>(K_conv, bt);
    k_gem<<<B_, 256, 0, stream>>>(h, W_h, b_h, gem);
    k_conv<<<2048, 256, 0, stream>>>(pad, bt, gem, b_conv, w_att, sp);
    float* alpha = out + B_ * C_;
    k_softmax<<<B_, 512, 0, stream>>>(sp, b_att, alpha);
    k_att<<<B_ * C_ / 4, 256, 0, stream>>>(conv_f, alpha, out);
}

// Round 8
// 527.671 us; speedup vs baseline: 1.0496x; 1.0496x over previous
//
#include <hip/hip_runtime.h>
#include <hip/hip_bf16.h>
#include <stdint.h>

#define B_ 128
#define C_ 512
#define H_ 8
#define W_ 64
#define L_ 512
#define EMB_ 512
#define HID_ 512
#define M_ 65536
#define PH 10
#define PW 66
#define PADSZ (B_*PH*PW*C_)     /* bf16 elements */
#define BT_SZ (9*EMB_*C_)       /* bf16 elements */
#define GEM_SZ (B_*EMB_)        /* f32 */

typedef __attribute__((ext_vector_type(8))) short short8;
typedef __attribute__((ext_vector_type(4))) float f32x4;

__device__ __forceinline__ void gload16(const void* g, void* l) {
    __builtin_amdgcn_global_load_lds(
        (const __attribute__((address_space(1))) unsigned int*)g,
        (__attribute__((address_space(3))) unsigned int*)l, 16, 0, 0);
}

__device__ __forceinline__ float fast_tanh(float x) {
    // tanh(|x|) = 1 - 2/(e^{2|x|}+1); exp(inf)->inf -> ratio 0 -> 1 (safe)
    float e = __expf(2.0f * fabsf(x));
    float r = 1.0f - __fdividef(2.0f, e + 1.0f);
    return copysignf(r, x);
}

// ---- pad + transpose conv_f [B,C,H,W] f32 -> padded channel-last bf16 [B][PH][PW][C]
__global__ __launch_bounds__(256) void k_pad(const float* __restrict__ cf,
                                             __hip_bfloat16* __restrict__ pad) {
    int bid = blockIdx.x, t = threadIdx.x;
    int b = bid >> 3, y = bid & 7;
    for (int cc = 0; cc < 2; ++cc) {
        int c = cc * 256 + t;
        const float* src = cf + ((size_t)(b * C_ + c) * H_ + y) * W_;
        __hip_bfloat16* dst = pad + ((size_t)(b * PH + y + 1) * PW + 1) * C_ + c;
#pragma unroll
        for (int x = 0; x < W_; ++x)
            dst[(size_t)x * C_] = __float2bfloat16(src[x]);
    }
}

// ---- K_conv [EMB,C,3,3] f32 -> Bt [tap][e][c] bf16
__global__ __launch_bounds__(256) void k_wt(const float* __restrict__ kc,
                                            __hip_bfloat16* __restrict__ bt) {
    int e = blockIdx.x, t = threadIdx.x;
    for (int cc = 0; cc < 2; ++cc) {
        int c = cc * 256 + t;
        const float* src = kc + (size_t)(e * C_ + c) * 9;
#pragma unroll
        for (int tap = 0; tap < 9; ++tap)
            bt[(size_t)tap * EMB_ * C_ + e * C_ + c] = __float2bfloat16(src[tap]);
    }
}

// ---- g_em = h @ W_h^T + b_h  (fp32)
__global__ __launch_bounds__(256) void k_gem(const float* __restrict__ h,
                                             const float* __restrict__ Wh,
                                             const float* __restrict__ bh,
                                             float* __restrict__ gem) {
    int b = blockIdx.x, t = threadIdx.x;
    __shared__ float hs[HID_];
    hs[t] = h[b * HID_ + t];
    hs[t + 256] = h[b * HID_ + t + 256];
    __syncthreads();
    for (int e = t; e < EMB_; e += 256) {
        float acc = bh[e];
        const float4* wr = (const float4*)(Wh + (size_t)e * HID_);
#pragma unroll 4
        for (int k4 = 0; k4 < HID_ / 4; ++k4) {
            float4 w = wr[k4];
            const float* hp = &hs[k4 * 4];
            acc += w.x * hp[0] + w.y * hp[1] + w.z * hp[2] + w.w * hp[3];
        }
        gem[b * EMB_ + e] = acc;
    }
}

// ---- main conv-GEMM: BM=BN=256, BK=64, 8 waves (2x4), double-buffered 128KiB LDS,
// 4-phase/iter pipeline with counted vmcnt (T3+T4) + setprio (T5). Swizzle per rule #21.
#define MFMA16(a,b,c) __builtin_amdgcn_mfma_f32_16x16x32_bf16(a,b,c,0,0,0)

__global__ __launch_bounds__(512, 2) void k_conv(const __hip_bfloat16* __restrict__ pad,
                                                 const __hip_bfloat16* __restrict__ bt,
                                                 const float* __restrict__ gem,
                                                 const float* __restrict__ bconv,
                                                 const float* __restrict__ watt,
                                                 float* __restrict__ sp) {
    __shared__ __align__(16) char lds[131072];   // buf k: A at k*65536, B at +32768
    const int tid = threadIdx.x;
    const int lane = tid & 63, wid = tid >> 6;
    const int wm = wid >> 2, wn = wid & 3;        // 2 x 4 wave grid
    int bid0 = blockIdx.x;
    int bid = (bid0 & 7) * 64 + (bid0 >> 3);      // XCD chunked swizzle (512 % 8 == 0)
    const int tile_m = bid >> 1, tile_n = bid & 1; // n-fast: adjacent bids share A-panel
    const int b = tile_m >> 1;

    // staging: LDS slot s holds logical (row, cbyte = (s&127) ^ ((row&7)<<4))
    int gA[4], gB[4];
#pragma unroll
    for (int i = 0; i < 4; ++i) {
        int s = i * 8192 + tid * 16;
        int row = s >> 7;                          // i*64 + tid>>3
        int clocal = ((s & 127) ^ ((row & 7) << 4)) >> 1;
        int m = tile_m * 256 + row;
        int y = (m >> 6) & 7;
        int x = m & 63;
        gA[i] = ((b * PH + y) * PW + x) * C_ + clocal;   // tap (0,0) base
        int e = tile_n * 256 + row;
        gB[i] = e * C_ + clocal;
    }
    const int lsw = wid * 1024;                    // wave-uniform LDS dest offset

    const int la = lane & 15, lg = lane >> 4;
    const int xorv = (la & 7) << 4;
    const int cb0 = (lg * 16) ^ xorv;              // kk = 0
    const int cb1 = (64 + lg * 16) ^ xorv;         // kk = 1

    f32x4 acc[8][4];
#pragma unroll
    for (int i = 0; i < 8; ++i)
#pragma unroll
        for (int j = 0; j < 4; ++j) acc[i][j] = (f32x4){0.f, 0.f, 0.f, 0.f};

#define STAGE_A(i, nb, aofs) gload16(pad + gA[i] + (aofs), lds + (nb)*65536 + (i)*8192 + lsw)
#define STAGE_B(i, nb, bofs) gload16(bt + gB[i] + (bofs), lds + (nb)*65536 + 32768 + (i)*8192 + lsw)

    // prologue: stage K-tile 0 into buf 0 (tap 0 -> aofs 0, bofs 0)
    STAGE_A(0, 0, 0); STAGE_A(1, 0, 0); STAGE_A(2, 0, 0); STAGE_A(3, 0, 0);
    STAGE_B(0, 0, 0); STAGE_B(1, 0, 0); STAGE_B(2, 0, 0); STAGE_B(3, 0, 0);

    for (int kt = 0; kt < 72; ++kt) {
        const int cur = kt & 1, nb = cur ^ 1;
        const char* bufA = lds + cur * 65536;
        const char* bufB = bufA + 32768;
        const int ktn = (kt < 71) ? kt + 1 : 71;   // last iter restages (never consumed)
        const int tapn = ktn >> 3;
        const int dyn_ = tapn / 3, dxn_ = tapn - dyn_ * 3;
        const int aofsn = (dyn_ * PW + dxn_) * C_ + ((ktn & 7) << 6);
        const int bofsn = tapn * (EMB_ * C_) + ((ktn & 7) << 6);

        short8 af[8], bq0, bq1;
        // ---- P1: prefetch A0,A1(next); counted wait for cur tile; kk0 x fn{0,1}
        STAGE_A(0, nb, aofsn); STAGE_A(1, nb, aofsn);
        asm volatile("s_waitcnt vmcnt(2)" ::: "memory");  // 8 cur-tile loads done, 2 fly
        __builtin_amdgcn_s_barrier();
#pragma unroll
        for (int fm = 0; fm < 8; ++fm)
            af[fm] = *(const short8*)(bufA + (wm * 128 + fm * 16 + la) * 128 + cb0);
        bq0 = *(const short8*)(bufB + (wn * 64 + la) * 128 + cb0);
        bq1 = *(const short8*)(bufB + (wn * 64 + 16 + la) * 128 + cb0);
        __builtin_amdgcn_s_setprio(1);
#pragma unroll
        for (int fm = 0; fm < 8; ++fm) {
            acc[fm][0] = MFMA16(af[fm], bq0, acc[fm][0]);
            acc[fm][1] = MFMA16(af[fm], bq1, acc[fm][1]);
        }
        __builtin_amdgcn_s_setprio(0);
        // ---- P2: prefetch A2,A3; kk0 x fn{2,3} (af reused)
        STAGE_A(2, nb, aofsn); STAGE_A(3, nb, aofsn);
        bq0 = *(const short8*)(bufB + (wn * 64 + 32 + la) * 128 + cb0);
        bq1 = *(const short8*)(bufB + (wn * 64 + 48 + la) * 128 + cb0);
        __builtin_amdgcn_s_setprio(1);
#pragma unroll
        for (int fm = 0; fm < 8; ++fm) {
            acc[fm][2] = MFMA16(af[fm], bq0, acc[fm][2]);
            acc[fm][3] = MFMA16(af[fm], bq1, acc[fm][3]);
        }
        __builtin_amdgcn_s_setprio(0);
        // ---- P3: prefetch B0,B1; kk1 x fn{0,1}
        STAGE_B(0, nb, bofsn); STAGE_B(1, nb, bofsn);
#pragma unroll
        for (int fm = 0; fm < 8; ++fm)
            af[fm] = *(const short8*)(bufA + (wm * 128 + fm * 16 + la) * 128 + cb1);
        bq0 = *(const short8*)(bufB + (wn * 64 + la) * 128 + cb1);
        bq1 = *(const short8*)(bufB + (wn * 64 + 16 + la) * 128 + cb1);
        __builtin_amdgcn_s_setprio(1);
#pragma unroll
        for (int fm = 0; fm < 8; ++fm) {
            acc[fm][0] = MFMA16(af[fm], bq0, acc[fm][0]);
            acc[fm][1] = MFMA16(af[fm], bq1, acc[fm][1]);
        }
        __builtin_amdgcn_s_setprio(0);
        // ---- P4: prefetch B2,B3; kk1 x fn{2,3}; end barrier frees cur buffer
        STAGE_B(2, nb, bofsn); STAGE_B(3, nb, bofsn);
        bq0 = *(const short8*)(bufB + (wn * 64 + 32 + la) * 128 + cb1);
        bq1 = *(const short8*)(bufB + (wn * 64 + 48 + la) * 128 + cb1);
        __builtin_amdgcn_s_setprio(1);
#pragma unroll
        for (int fm = 0; fm < 8; ++fm) {
            acc[fm][2] = MFMA16(af[fm], bq0, acc[fm][2]);
            acc[fm][3] = MFMA16(af[fm], bq1, acc[fm][3]);
        }
        __builtin_amdgcn_s_setprio(0);
        __builtin_amdgcn_s_barrier();
    }
    asm volatile("s_waitcnt vmcnt(0)" ::: "memory");  // retire dangling LDS writes

    // epilogue: score_part[part][m] = sum_e fast_tanh(conv + b_conv + g_em) * w_att
    const int part = tile_n * 4 + wn;
    float addv[4], wv[4];
#pragma unroll
    for (int fn = 0; fn < 4; ++fn) {
        int e = tile_n * 256 + wn * 64 + fn * 16 + la;
        addv[fn] = bconv[e] + gem[b * EMB_ + e];
        wv[fn] = watt[e];
    }
#pragma unroll
    for (int fm = 0; fm < 8; ++fm) {
        float sj[4] = {0.f, 0.f, 0.f, 0.f};
#pragma unroll
        for (int fn = 0; fn < 4; ++fn)
#pragma unroll
            for (int j = 0; j < 4; ++j)
                sj[j] += fast_tanh(acc[fm][fn][j] + addv[fn]) * wv[fn];
#pragma unroll
        for (int mask = 1; mask < 16; mask <<= 1)
#pragma unroll
            for (int j = 0; j < 4; ++j)
                sj[j] += __shfl_xor(sj[j], mask, 64);
        if (la == 0) {
            int mrow = tile_m * 256 + wm * 128 + fm * 16 + lg * 4;
            *(float4*)(sp + (size_t)part * M_ + mrow) =
                make_float4(sj[0], sj[1], sj[2], sj[3]);
        }
    }
}

// ---- softmax over L per batch: score = b_att + sum parts -> alpha (written to d_out)
__global__ __launch_bounds__(512) void k_softmax(const float* __restrict__ sp,
                                                 const float* __restrict__ batt,
                                                 float* __restrict__ alpha) {
    int b = blockIdx.x, t = threadIdx.x;
    float s = batt[0];
#pragma unroll
    for (int p = 0; p < 8; ++p) s += sp[(size_t)p * M_ + b * L_ + t];
    int lane = t & 63, wid = t >> 6;
    __shared__ float red[8];
    float m = s;
#pragma unroll
    for (int mask = 1; mask < 64; mask <<= 1) m = fmaxf(m, __shfl_xor(m, mask, 64));
    if (lane == 0) red[wid] = m;
    __syncthreads();
    float M = red[0];
#pragma unroll
    for (int i = 1; i < 8; ++i) M = fmaxf(M, red[i]);
    float ev = __expf(s - M);
    float sum = ev;
#pragma unroll
    for (int mask = 1; mask < 64; mask <<= 1) sum += __shfl_xor(sum, mask, 64);
    __syncthreads();
    if (lane == 0) red[wid] = sum;
    __syncthreads();
    float S = 0.f;
#pragma unroll
    for (int i = 0; i < 8; ++i) S += red[i];
    alpha[b * L_ + t] = ev / S;
}

// ---- att_out[b,c] = sum_l alpha[b,l] * conv_f[b,c,l]  (f32, coalesced)
__global__ __launch_bounds__(256) void k_att(const float* __restrict__ cf,
                                             const float* __restrict__ alpha,
                                             float* __restrict__ att) {
    int bid = blockIdx.x;
    int b = bid >> 7, cg = bid & 127;
    int t = threadIdx.x, lane = t & 63, wid = t >> 6;
    int c = cg * 4 + wid;
    const float4* xr = (const float4*)(cf + (size_t)(b * C_ + c) * L_);
    const float4* ar = (const float4*)(alpha + b * L_);
    float acc = 0.f;
#pragma unroll
    for (int it = 0; it < 2; ++it) {
        float4 xv = xr[it * 64 + lane];
        float4 av = ar[it * 64 + lane];
        acc += xv.x * av.x + xv.y * av.y + xv.z * av.z + xv.w * av.w;
    }
#pragma unroll
    for (int mask = 1; mask < 64; mask <<= 1) acc += __shfl_xor(acc, mask, 64);
    if (lane == 0) att[b * C_ + c] = acc;
}

extern "C" void kernel_launch(void* const* d_in, const int* in_sizes, int n_in,
                              void* d_out, int out_size, void* d_ws, size_t ws_size,
                              hipStream_t stream) {
    const float* conv_f = (const float*)d_in[0];
    const float* h      = (const float*)d_in[1];
    const float* W_h    = (const float*)d_in[2];
    const float* b_h    = (const float*)d_in[3];
    const float* K_conv = (const float*)d_in[4];
    const float* b_conv = (const float*)d_in[5];
    const float* w_att  = (const float*)d_in[6];
    const float* b_att  = (const float*)d_in[7];
    float* out = (float*)d_out;              // [B*C] att_out then [B*L] alpha

    char* ws = (char*)d_ws;
    __hip_bfloat16* pad = (__hip_bfloat16*)ws;
    __hip_bfloat16* bt  = (__hip_bfloat16*)(ws + (size_t)PADSZ * 2);
    float* gem = (float*)(ws + (size_t)PADSZ * 2 + (size_t)BT_SZ * 2);
    float* sp  = gem + GEM_SZ;               // 8 * M_ floats

    hipMemsetAsync(pad, 0, (size_t)PADSZ * 2, stream);
    k_pad<<<B_ * H_, 256, 0, stream>>>(conv_f, pad);
    k_wt<<<EMB_, 256, 0, stream>>>(K_conv, bt);
    k_gem<<<B_, 256, 0, stream>>>(h, W_h, b_h, gem);
    k_conv<<<512, 512, 0, stream>>>(pad, bt, gem, b_conv, w_att, sp);
    float* alpha = out + B_ * C_;
    k_softmax<<<B_, 512, 0, stream>>>(sp, b_att, alpha);
    k_att<<<B_ * C_ / 4, 256, 0, stream>>>(conv_f, alpha, out);
}